// Round 2
// baseline (120.157 us; speedup 1.0000x reference)
//
#include <hip/hip_runtime.h>
#include <math.h>

// LRPCHead: C=512, H=W=160 (HW=25600), NC=1203, LC=64
// Outputs (flat, fp32): loc_out [64*25600] | cls_out [1203*25600] | mask [25600]

constexpr int C_   = 512;
constexpr int HW_  = 25600;
constexpr int NC_  = 1203;

constexpr int LOC_OFF_  = 0;
constexpr int CLS_OFF_  = 64 * HW_;              // 1,638,400
constexpr int MASK_OFF_ = CLS_OFF_ + NC_ * HW_;  // 32,435,200

// ---------------------------------------------------------------- init
__global__ void k_init(int* cnt) { *cnt = 0; }

// ------------------------------------------------- pf score + mask + compact
// block = 256 threads = 64 hw-columns x 4 C-slices of 128
__global__ __launch_bounds__(256) void k_pf_mask(
    const float* __restrict__ cls_feat, const float* __restrict__ pf_w,
    const float* __restrict__ pf_b, const float* __restrict__ conf,
    float* __restrict__ out, int* __restrict__ cnt,
    int* __restrict__ idxList)
{
    __shared__ double sPart[256];
    const int tid   = threadIdx.x;
    const int hwi   = tid & 63;
    const int slice = tid >> 6;
    const int hw    = blockIdx.x * 64 + hwi;
    const float* p  = cls_feat + (size_t)slice * 128 * HW_ + hw;
    const float* w  = pf_w + slice * 128;
    double acc = 0.0;
    #pragma unroll 4
    for (int k = 0; k < 128; ++k)
        acc += (double)w[k] * (double)p[(size_t)k * HW_];
    sPart[tid] = acc;
    __syncthreads();
    if (slice == 0) {
        double s = sPart[hwi] + sPart[64 + hwi] + sPart[128 + hwi] +
                   sPart[192 + hwi] + (double)pf_b[0];
        double sig = 1.0 / (1.0 + exp(-s));
        bool m = sig > (double)conf[0];
        out[MASK_OFF_ + hw] = m ? 1.0f : 0.0f;
        if (m) {
            int pos = atomicAdd(cnt, 1);
            if (pos < HW_) idxList[pos] = hw;
        }
    }
}

// ------------------------------------------------- fill cls_out with vocab_b
__global__ __launch_bounds__(256) void k_fill_cls(
    const float* __restrict__ vocab_b, float* __restrict__ out)
{
    const int total4 = NC_ * HW_ / 4;  // 7,699,200 16B-chunks
    float4* o = (float4*)(out + CLS_OFF_);
    for (int i = blockIdx.x * 256 + threadIdx.x; i < total4;
         i += gridDim.x * 256) {
        int v = i / (HW_ / 4);
        float b = vocab_b[v];
        o[i] = make_float4(b, b, b, b);
    }
}

// ------------------------------------------------- loc 1x1 conv (64x64)
// grid (HW/256, 4): block handles 256 hw-cols x 16 out-channels
__global__ __launch_bounds__(256) void k_loc(
    const float* __restrict__ loc_feat, const float* __restrict__ loc_w,
    const float* __restrict__ loc_b, float* __restrict__ out)
{
    __shared__ float sw[16][64];
    const int tid = threadIdx.x;
    const int o0  = blockIdx.y * 16;
    for (int i = tid; i < 16 * 64; i += 256)
        sw[i >> 6][i & 63] = loc_w[(o0 + (i >> 6)) * 64 + (i & 63)];
    __syncthreads();

    const int hw = blockIdx.x * 256 + tid;
    float acc[16];
    #pragma unroll
    for (int r = 0; r < 16; ++r) acc[r] = loc_b[o0 + r];
    for (int i = 0; i < 64; ++i) {
        float f = loc_feat[(size_t)i * HW_ + hw];
        #pragma unroll
        for (int r = 0; r < 16; ++r) acc[r] += sw[r][i] * f;
    }
    #pragma unroll
    for (int r = 0; r < 16; ++r)
        out[LOC_OFF_ + (size_t)(o0 + r) * HW_ + hw] = acc[r];
}

// --------------------------------------- sparse GEMM over compacted columns
// 64v x 64j tile per block, K-step 16, fp32 VALU. Blocks past `count` exit.
__global__ __launch_bounds__(256) void k_gemm_scatter(
    const float* __restrict__ cls_feat, const float* __restrict__ vocab_w,
    const float* __restrict__ vocab_b, const int* __restrict__ cnt,
    const int* __restrict__ idxList, float* __restrict__ out)
{
    const int count = min(*cnt, HW_);
    const int j0 = blockIdx.y * 64;
    if (j0 >= count) return;
    const int v0 = blockIdx.x * 64;

    __shared__ float sAT[16][64];  // [kk][v-row]
    __shared__ float sBT[16][64];  // [kk][j-col]
    __shared__ int   sIdx[64];

    const int tid = threadIdx.x;
    if (tid < 64) {
        int j = j0 + tid;
        sIdx[tid] = (j < count) ? idxList[j] : -1;
    }
    __syncthreads();

    const int tx = tid & 15;   // j dir
    const int ty = tid >> 4;   // v dir
    const int r  = tid >> 2;   // loader row 0..63
    const int kq = tid & 3;    // loader k-quad 0..3
    const int hwj = sIdx[r];

    float acc[4][4] = {};

    for (int k0 = 0; k0 < C_; k0 += 16) {
        float4 a4 = make_float4(0.f, 0.f, 0.f, 0.f);
        if (v0 + r < NC_)
            a4 = *(const float4*)(vocab_w + (size_t)(v0 + r) * C_ + k0 + kq * 4);
        float b0 = 0.f, b1 = 0.f, b2 = 0.f, b3 = 0.f;
        if (hwj >= 0) {
            const float* bp = cls_feat + (size_t)(k0 + kq * 4) * HW_ + hwj;
            b0 = bp[0]; b1 = bp[HW_]; b2 = bp[2 * HW_]; b3 = bp[3 * HW_];
        }
        __syncthreads();
        sAT[kq * 4 + 0][r] = a4.x;
        sAT[kq * 4 + 1][r] = a4.y;
        sAT[kq * 4 + 2][r] = a4.z;
        sAT[kq * 4 + 3][r] = a4.w;
        sBT[kq * 4 + 0][r] = b0;
        sBT[kq * 4 + 1][r] = b1;
        sBT[kq * 4 + 2][r] = b2;
        sBT[kq * 4 + 3][r] = b3;
        __syncthreads();

        #pragma unroll
        for (int kk = 0; kk < 16; ++kk) {
            const float4 av = *(const float4*)&sAT[kk][ty * 4];
            const float4 bv = *(const float4*)&sBT[kk][tx * 4];
            acc[0][0] += av.x * bv.x; acc[0][1] += av.x * bv.y;
            acc[0][2] += av.x * bv.z; acc[0][3] += av.x * bv.w;
            acc[1][0] += av.y * bv.x; acc[1][1] += av.y * bv.y;
            acc[1][2] += av.y * bv.z; acc[1][3] += av.y * bv.w;
            acc[2][0] += av.z * bv.x; acc[2][1] += av.z * bv.y;
            acc[2][2] += av.z * bv.z; acc[2][3] += av.z * bv.w;
            acc[3][0] += av.w * bv.x; acc[3][1] += av.w * bv.y;
            acc[3][2] += av.w * bv.z; acc[3][3] += av.w * bv.w;
        }
    }

    #pragma unroll
    for (int a = 0; a < 4; ++a) {
        int v = v0 + ty * 4 + a;
        if (v >= NC_) continue;
        float bias = vocab_b[v];
        #pragma unroll
        for (int b = 0; b < 4; ++b) {
            int j = j0 + tx * 4 + b;
            if (j < count) {
                int hw = sIdx[tx * 4 + b];
                out[CLS_OFF_ + (size_t)v * HW_ + hw] = acc[a][b] + bias;
            }
        }
    }
}

// ----------------------------------------------------------------- launch
extern "C" void kernel_launch(void* const* d_in, const int* in_sizes, int n_in,
                              void* d_out, int out_size, void* d_ws,
                              size_t ws_size, hipStream_t stream) {
    const float* cls_feat = (const float*)d_in[0];
    const float* loc_feat = (const float*)d_in[1];
    const float* conf     = (const float*)d_in[2];
    const float* pf_w     = (const float*)d_in[3];
    const float* pf_b     = (const float*)d_in[4];
    const float* vocab_w  = (const float*)d_in[5];
    const float* vocab_b  = (const float*)d_in[6];
    const float* loc_w    = (const float*)d_in[7];
    const float* loc_b    = (const float*)d_in[8];
    float* out = (float*)d_out;

    int* cnt     = (int*)d_ws;
    int* idxList = (int*)((char*)d_ws + 256);

    hipLaunchKernelGGL(k_init, dim3(1), dim3(1), 0, stream, cnt);
    hipLaunchKernelGGL(k_pf_mask, dim3(HW_ / 64), dim3(256), 0, stream,
                       cls_feat, pf_w, pf_b, conf, out, cnt, idxList);
    hipLaunchKernelGGL(k_fill_cls, dim3(2048), dim3(256), 0, stream,
                       vocab_b, out);
    hipLaunchKernelGGL(k_loc, dim3(HW_ / 256, 4), dim3(256), 0, stream,
                       loc_feat, loc_w, loc_b, out);
    hipLaunchKernelGGL(k_gemm_scatter,
                       dim3((NC_ + 63) / 64, (HW_ + 63) / 64), dim3(256), 0,
                       stream, cls_feat, vocab_w, vocab_b, cnt, idxList, out);
}